// Round 1
// 161.062 us; speedup vs baseline: 1.0505x; 1.0505x over previous
//
#include <hip/hip_runtime.h>
#include <math.h>

#define EPS 1e-7f
#define REG_MAX 16
#define A_DIM 8400

// d_ws layout (floats): p_liou[0..2047], p_dfl[2048..4095], p_nfg[4096..6143]
// (one slot per block, written unconditionally -> no memset, no atomics)

__global__ __launch_bounds__(256) void bbox_loss_fused(
    const float* __restrict__ pred_dist,      // (B,A,64)
    const float* __restrict__ pred_bboxes,    // (B,A,4)
    const float* __restrict__ anchor_points,  // (A,2)
    const float* __restrict__ target_bboxes,  // (B,A,4)
    const float* __restrict__ target_scores,  // (B,A,80)
    const int*   __restrict__ fg_mask,        // (B,A) int32
    float* __restrict__ p_liou,
    float* __restrict__ p_dfl,
    float* __restrict__ p_nfg,
    int total)
{
    __shared__ int s_idx[256];
    __shared__ int s_wtot[4];
    __shared__ int s_woff[4];
    __shared__ int s_cnt;

    const int tid  = threadIdx.x;
    const int i0   = blockIdx.x * 256 + tid;
    const int wave = tid >> 6;
    const int lane = tid & 63;

    // ---- block-local stream compaction into LDS ----
    const bool fg = (i0 < total) && (fg_mask[i0] != 0);
    const unsigned long long ball = __ballot(fg);
    const int pre = __popcll(ball & ((1ull << lane) - 1ull));
    if (lane == 0) s_wtot[wave] = __popcll(ball);
    __syncthreads();
    if (tid == 0) {
        int off = 0;
        #pragma unroll
        for (int k = 0; k < 4; ++k) { s_woff[k] = off; off += s_wtot[k]; }
        s_cnt = off;
    }
    __syncthreads();
    if (fg) s_idx[s_woff[wave] + pre] = i0;
    __syncthreads();
    const int cnt = s_cnt;

    // ---- cooperative processing: 4 lanes (one quad) per fg item ----
    // lane q in the quad owns side q (l,t,r,b): full 16-bin softmax is
    // lane-local -> zero shuffles in the DFL path.
    float liou = 0.f, ldfl = 0.f;

    const int gq = tid >> 2;   // quad id 0..63
    const int q  = tid & 3;    // side 0..3

    for (int j = gq; j < cnt; j += 64) {
        const int i = s_idx[j];
        const int a = i % A_DIM;

        // issue all independent loads up front
        const float4* ts4 = (const float4*)(target_scores + (size_t)i * 80);
        const float4 s0 = ts4[q];
        const float4 s1 = ts4[q + 4];
        const float4 s2 = ts4[q + 8];
        const float4 s3 = ts4[q + 12];
        const float4 s4 = ts4[q + 16];

        const float4 tb  = *(const float4*)(target_bboxes + (size_t)i * 4);
        const float2 apt = *(const float2*)(anchor_points + 2 * (size_t)a);

        const float4* pd4 = (const float4*)(pred_dist + (size_t)i * 64) + (q << 2);
        const float4 b0 = pd4[0];
        const float4 b1 = pd4[1];
        const float4 b2 = pd4[2];
        const float4 b3 = pd4[3];

        // weight = sum of 80 class scores (20 float4s spread over the quad)
        float w = ((s0.x + s0.y) + (s0.z + s0.w))
                + ((s1.x + s1.y) + (s1.z + s1.w))
                + ((s2.x + s2.y) + (s2.z + s2.w))
                + ((s3.x + s3.y) + (s3.z + s3.w))
                + ((s4.x + s4.y) + (s4.z + s4.w));
        w += __shfl_xor(w, 1);
        w += __shfl_xor(w, 2);

        // ---- DFL: lane-local 16-bin log-softmax for side q ----
        float tq = (q == 0) ? (apt.x - tb.x) : (q == 1) ? (apt.y - tb.y)
                 : (q == 2) ? (tb.z - apt.x) : (tb.w - apt.y);
        tq = fminf(fmaxf(tq, 0.f), (float)(REG_MAX - 1) - 0.01f);

        float m = fmaxf(
            fmaxf(fmaxf(fmaxf(b0.x, b0.y), fmaxf(b0.z, b0.w)),
                  fmaxf(fmaxf(b1.x, b1.y), fmaxf(b1.z, b1.w))),
            fmaxf(fmaxf(fmaxf(b2.x, b2.y), fmaxf(b2.z, b2.w)),
                  fmaxf(fmaxf(b3.x, b3.y), fmaxf(b3.z, b3.w))));
        float se = (__expf(b0.x - m) + __expf(b0.y - m))
                 + (__expf(b0.z - m) + __expf(b0.w - m))
                 + (__expf(b1.x - m) + __expf(b1.y - m))
                 + (__expf(b1.z - m) + __expf(b1.w - m))
                 + (__expf(b2.x - m) + __expf(b2.y - m))
                 + (__expf(b2.z - m) + __expf(b2.w - m))
                 + (__expf(b3.x - m) + __expf(b3.y - m))
                 + (__expf(b3.z - m) + __expf(b3.w - m));
        const float lse = m + __logf(se);

        const int   tl = (int)tq;
        const int   tr = min(tl + 1, REG_MAX - 1);
        const float wl = (float)(tl + 1) - tq;
        const float wr = 1.f - wl;

        // branchless gather of x[tl], x[tr] (no runtime register indexing)
        int hi = tl >> 2, lo = tl & 3;
        float4 f = (hi == 0) ? b0 : (hi == 1) ? b1 : (hi == 2) ? b2 : b3;
        const float xl = (lo == 0) ? f.x : (lo == 1) ? f.y : (lo == 2) ? f.z : f.w;
        hi = tr >> 2; lo = tr & 3;
        f = (hi == 0) ? b0 : (hi == 1) ? b1 : (hi == 2) ? b2 : b3;
        const float xr = (lo == 0) ? f.x : (lo == 1) ? f.y : (lo == 2) ? f.z : f.w;

        // ce_l*wl + ce_r*wr = lse*(wl+wr) - (wl*xl + wr*xr); wl+wr == 1
        ldfl += lse - (wl * xl + wr * xr);

        // ---- CIoU on the quad leader (amortized over 16 items/wave) ----
        if (q == 0) {
            const float4 pb = *(const float4*)(pred_bboxes + (size_t)i * 4);
            const float x11 = pb.x, y11 = pb.y, x21 = pb.z, y21 = pb.w;
            const float x12 = tb.x, y12 = tb.y, x22 = tb.z, y22 = tb.w;
            const float iw = fmaxf(fminf(x21, x22) - fmaxf(x11, x12), 0.f);
            const float ih = fmaxf(fminf(y21, y22) - fmaxf(y11, y12), 0.f);
            const float inter = iw * ih;
            const float w1 = x21 - x11, h1 = y21 - y11;
            const float w2 = x22 - x12, h2 = y22 - y12;
            const float uni = w1 * h1 + w2 * h2 - inter + EPS;
            const float iou = inter / uni;
            const float cw = fmaxf(x21, x22) - fminf(x11, x12);
            const float ch = fmaxf(y21, y22) - fminf(y11, y12);
            const float c2 = cw * cw + ch * ch + EPS;
            const float dx = x11 + x21 - x12 - x22;
            const float dy = y11 + y21 - y12 - y22;
            const float rho2 = (dx * dx + dy * dy) * 0.25f;
            const float dang = atanf(w1 / (h1 + EPS)) - atanf(w2 / (h2 + EPS));
            const float vv = (4.f / (float)(M_PI * M_PI)) * dang * dang;
            const float alpha = vv / (1.f - iou + vv + EPS);
            const float ciou = iou - (rho2 / c2 + vv * alpha);
            liou += (1.f - ciou) * w;
        }
    }

    // ---- block reduction -> per-block partial slots (no atomics) ----
    #pragma unroll
    for (int off = 32; off >= 1; off >>= 1) {
        liou += __shfl_down(liou, off);
        ldfl += __shfl_down(ldfl, off);
    }
    __shared__ float r0[4], r1[4];
    if (lane == 0) { r0[wave] = liou; r1[wave] = ldfl; }
    __syncthreads();
    if (tid == 0) {
        p_liou[blockIdx.x] = r0[0] + r0[1] + r0[2] + r0[3];
        p_dfl[blockIdx.x]  = r1[0] + r1[1] + r1[2] + r1[3];
        p_nfg[blockIdx.x]  = (float)cnt;
    }
}

__global__ __launch_bounds__(256) void bbox_loss_finalize(
    const float* __restrict__ p_liou,
    const float* __restrict__ p_dfl,
    const float* __restrict__ p_nfg,
    int nb,
    const float* __restrict__ tss,
    float* __restrict__ out)
{
    const int tid = threadIdx.x;
    float a = 0.f, b = 0.f, c = 0.f;
    for (int k = tid; k < nb; k += 256) {
        a += p_liou[k];
        b += p_dfl[k];
        c += p_nfg[k];
    }
    #pragma unroll
    for (int off = 32; off >= 1; off >>= 1) {
        a += __shfl_down(a, off);
        b += __shfl_down(b, off);
        c += __shfl_down(c, off);
    }
    __shared__ float r0[4], r1[4], r2[4];
    const int wave = tid >> 6, lane = tid & 63;
    if (lane == 0) { r0[wave] = a; r1[wave] = b; r2[wave] = c; }
    __syncthreads();
    if (tid == 0) {
        const float A = r0[0] + r0[1] + r0[2] + r0[3];
        const float Bs = r1[0] + r1[1] + r1[2] + r1[3];
        const float C = r2[0] + r2[1] + r2[2] + r2[3];
        out[0] = A / tss[0];
        out[1] = Bs / fmaxf(C * 4.f, 1.f);
    }
}

extern "C" void kernel_launch(void* const* d_in, const int* in_sizes, int n_in,
                              void* d_out, int out_size, void* d_ws, size_t ws_size,
                              hipStream_t stream) {
    const float* pred_dist     = (const float*)d_in[0];
    const float* pred_bboxes   = (const float*)d_in[1];
    const float* anchor_points = (const float*)d_in[2];
    const float* target_bboxes = (const float*)d_in[3];
    const float* target_scores = (const float*)d_in[4];
    const float* tss           = (const float*)d_in[5];
    const int*   fg_mask       = (const int*)d_in[6];
    float* out = (float*)d_out;

    float* p_liou = (float*)d_ws;
    float* p_dfl  = p_liou + 2048;
    float* p_nfg  = p_liou + 4096;

    const int total = in_sizes[6];               // B*A = 268800
    const int nb = (total + 255) / 256;          // 1050

    bbox_loss_fused<<<nb, 256, 0, stream>>>(pred_dist, pred_bboxes, anchor_points,
                                            target_bboxes, target_scores, fg_mask,
                                            p_liou, p_dfl, p_nfg, total);
    bbox_loss_finalize<<<1, 256, 0, stream>>>(p_liou, p_dfl, p_nfg, nb, tss, out);
}